// Round 1
// baseline (118.011 us; speedup 1.0000x reference)
//
#include <hip/hip_runtime.h>
#include <stdint.h>

#define NN 4096
#define DD 512
#define NH 3
#define MAXDEG 256   // mean degree ~41, sd ~6.4; 256 is >30 sigma headroom

typedef float f4v __attribute__((ext_vector_type(4)));

__device__ __forceinline__ unsigned short f2bf_rn(float x) {
    union { float f; uint32_t u; } v; v.f = x;
    uint32_t u = v.u;
    uint32_t r = (u + 0x7FFFu + ((u >> 16) & 1u)) >> 16;
    return (unsigned short)r;
}
__device__ __forceinline__ float bflo(uint32_t u) {
    union { uint32_t u; float f; } v; v.u = u << 16; return v.f;
}
__device__ __forceinline__ float bfhi(uint32_t u) {
    union { uint32_t u; float f; } v; v.u = u & 0xFFFF0000u; return v.f;
}

// Kernel A: one wave per node j. Computes w[j][h] = exp(relu(h[j]·P[:,h]))
// and writes a round-to-nearest bf16 copy of h[j,:] (halves gather traffic,
// keeps the gather table at 4MB so it caches well).
__global__ __launch_bounds__(256) void prep_kernel(
    const float* __restrict__ h, const float* __restrict__ P,
    float* __restrict__ w, unsigned short* __restrict__ hb)
{
    int gid = blockIdx.x * 256 + threadIdx.x;
    int row = gid >> 6, ln = gid & 63;
    const f4v* h4 = (const f4v*)(h + (size_t)row * DD);
    // h fp32 is never read again -> stream it (nt) so it doesn't evict anything
    f4v va = __builtin_nontemporal_load(&h4[ln * 2]);
    f4v vb = __builtin_nontemporal_load(&h4[ln * 2 + 1]);
    float e[8] = { va[0], va[1], va[2], va[3], vb[0], vb[1], vb[2], vb[3] };

    // pack 8 bf16 -> 16B coalesced store (cached: att_agg reads this next)
    uint32_t pk0 = (uint32_t)f2bf_rn(e[0]) | ((uint32_t)f2bf_rn(e[1]) << 16);
    uint32_t pk1 = (uint32_t)f2bf_rn(e[2]) | ((uint32_t)f2bf_rn(e[3]) << 16);
    uint32_t pk2 = (uint32_t)f2bf_rn(e[4]) | ((uint32_t)f2bf_rn(e[5]) << 16);
    uint32_t pk3 = (uint32_t)f2bf_rn(e[6]) | ((uint32_t)f2bf_rn(e[7]) << 16);
    uint4 pk = make_uint4(pk0, pk1, pk2, pk3);
    *(uint4*)(hb + (size_t)row * DD + ln * 8) = pk;

    // partial dots (each lane covers d = ln*8 .. ln*8+7; P is 6KB, L1-resident)
    int d0 = ln * 8;
    float a0 = 0.f, a1 = 0.f, a2 = 0.f;
    #pragma unroll
    for (int k = 0; k < 8; ++k) {
        float hv = e[k];
        const float* Pr = P + (size_t)(d0 + k) * NH;
        a0 = fmaf(hv, Pr[0], a0);
        a1 = fmaf(hv, Pr[1], a1);
        a2 = fmaf(hv, Pr[2], a2);
    }
    #pragma unroll
    for (int off = 32; off > 0; off >>= 1) {
        a0 += __shfl_down(a0, off);
        a1 += __shfl_down(a1, off);
        a2 += __shfl_down(a2, off);
    }
    if (ln == 0) {
        w[row * NH + 0] = expf(fmaxf(a0, 0.f));
        w[row * NH + 1] = expf(fmaxf(a1, 0.f));
        w[row * NH + 2] = expf(fmaxf(a2, 0.f));
    }
}

// Kernel B: ONE WAVE per output row i (4 independent waves per block).
// No __syncthreads, no LDS atomics, no cross-wave combine.
// Phase 1: wave scans its 16KB graph row (nt loads), ballot-compacts nonzero
//          columns into wave-private LDS; running count stays in an SGPR.
// Phase 1.5: Z[3] over compacted list (strided per-lane + shfl_xor reduce),
//          then combined per-neighbor coefficient c_j = RS * sum_h w[j][h]/Z[h].
// Phase 2: 4 neighbors/iter; each lane loads 16B (8 bf16) of each neighbor row
//          -> one wave covers the full D=512 row per load, fully coalesced.
__global__ __launch_bounds__(256) void att_agg_kernel(
    const float* __restrict__ g, const unsigned short* __restrict__ hb,
    const float* __restrict__ w, float* __restrict__ out)
{
    __shared__ int   s_idx[4][MAXDEG + 8];
    __shared__ float s_c[4][MAXDEG + 8];

    const int wv = threadIdx.x >> 6, ln = threadIdx.x & 63;
    const int row = blockIdx.x * 4 + wv;
    int*   __restrict__ idxb = s_idx[wv];
    float* __restrict__ cb   = s_c[wv];

    // ---- Phase 1: scan 16KB graph row, wave-private compact ----
    const f4v* g4 = (const f4v*)(g + (size_t)row * NN);
    int cnt = 0;   // wave-uniform (ballot/popc) -> lives in SGPR
    #pragma unroll 4
    for (int it = 0; it < (NN / 4) / 64; ++it) {   // 16 iterations
        f4v v = __builtin_nontemporal_load(&g4[it * 64 + ln]);  // stream, don't evict hb
        int base = (it * 64 + ln) * 4;
        #pragma unroll
        for (int k = 0; k < 4; ++k) {
            bool p = v[k] > 0.f;
            unsigned long long m = __ballot(p);
            if (m) {   // wave-uniform
                if (p) {
                    unsigned pre = __builtin_amdgcn_mbcnt_lo((unsigned)m, 0u);
                    pre = __builtin_amdgcn_mbcnt_hi((unsigned)(m >> 32), pre);
                    int pos = cnt + (int)pre;
                    if (pos < MAXDEG) idxb[pos] = base + k;
                }
                cnt += __popcll(m);
            }
        }
    }
    int nnz = cnt > MAXDEG ? MAXDEG : cnt;

    float* orow = out + (size_t)row * DD + ln * 8;
    if (nnz == 0) {   // zero-degree row: rowsum=0 => output 0 (wave-uniform)
        f4v z = {0.f, 0.f, 0.f, 0.f};
        __builtin_nontemporal_store(z, (f4v*)orow);
        __builtin_nontemporal_store(z, (f4v*)(orow + 4));
        return;
    }

    __builtin_amdgcn_wave_barrier();   // compiler fence: LDS writes before reads

    // ---- Phase 1.5a: Z over compacted list ----
    float z0 = 0.f, z1 = 0.f, z2 = 0.f;
    for (int t = ln; t < nnz; t += 64) {
        int j = idxb[t];
        const float* wr = w + (size_t)j * NH;
        z0 += wr[0]; z1 += wr[1]; z2 += wr[2];
    }
    #pragma unroll
    for (int off = 32; off > 0; off >>= 1) {
        z0 += __shfl_xor(z0, off);
        z1 += __shfl_xor(z1, off);
        z2 += __shfl_xor(z2, off);
    }
    float RS = (float)nnz;   // binary graph: rowsum == degree
    float sc0 = RS / z0, sc1 = RS / z1, sc2 = RS / z2;

    // ---- Phase 1.5b: per-neighbor combined coefficient (+ pad to x4) ----
    int npad = (nnz + 3) & ~3;
    for (int t = ln; t < npad; t += 64) {
        if (t < nnz) {
            int j = idxb[t];
            const float* wr = w + (size_t)j * NH;   // L1-hit (just loaded)
            cb[t] = fmaf(sc0, wr[0], fmaf(sc1, wr[1], sc2 * wr[2]));
        } else {
            idxb[t] = idxb[0];
            cb[t] = 0.f;
        }
    }
    __builtin_amdgcn_wave_barrier();

    // ---- Phase 2: out[row,:] = sum_t c_t * hb[j_t,:]  (4 neighbors/iter) ----
    const unsigned short* hcol = hb + ln * 8;
    float acc0=0.f,acc1=0.f,acc2=0.f,acc3=0.f,acc4=0.f,acc5=0.f,acc6=0.f,acc7=0.f;
    for (int t = 0; t < npad; t += 4) {
        int j0 = idxb[t+0]; float c0 = cb[t+0];
        int j1 = idxb[t+1]; float c1 = cb[t+1];
        int j2 = idxb[t+2]; float c2 = cb[t+2];
        int j3 = idxb[t+3]; float c3 = cb[t+3];
        uint4 r0 = *(const uint4*)(hcol + (size_t)j0 * DD);
        uint4 r1 = *(const uint4*)(hcol + (size_t)j1 * DD);
        uint4 r2 = *(const uint4*)(hcol + (size_t)j2 * DD);
        uint4 r3 = *(const uint4*)(hcol + (size_t)j3 * DD);
        acc0 = fmaf(c0, bflo(r0.x), acc0); acc1 = fmaf(c0, bfhi(r0.x), acc1);
        acc2 = fmaf(c0, bflo(r0.y), acc2); acc3 = fmaf(c0, bfhi(r0.y), acc3);
        acc4 = fmaf(c0, bflo(r0.z), acc4); acc5 = fmaf(c0, bfhi(r0.z), acc5);
        acc6 = fmaf(c0, bflo(r0.w), acc6); acc7 = fmaf(c0, bfhi(r0.w), acc7);
        acc0 = fmaf(c1, bflo(r1.x), acc0); acc1 = fmaf(c1, bfhi(r1.x), acc1);
        acc2 = fmaf(c1, bflo(r1.y), acc2); acc3 = fmaf(c1, bfhi(r1.y), acc3);
        acc4 = fmaf(c1, bflo(r1.z), acc4); acc5 = fmaf(c1, bfhi(r1.z), acc5);
        acc6 = fmaf(c1, bflo(r1.w), acc6); acc7 = fmaf(c1, bfhi(r1.w), acc7);
        acc0 = fmaf(c2, bflo(r2.x), acc0); acc1 = fmaf(c2, bfhi(r2.x), acc1);
        acc2 = fmaf(c2, bflo(r2.y), acc2); acc3 = fmaf(c2, bfhi(r2.y), acc3);
        acc4 = fmaf(c2, bflo(r2.z), acc4); acc5 = fmaf(c2, bfhi(r2.z), acc5);
        acc6 = fmaf(c2, bflo(r2.w), acc6); acc7 = fmaf(c2, bfhi(r2.w), acc7);
        acc0 = fmaf(c3, bflo(r3.x), acc0); acc1 = fmaf(c3, bfhi(r3.x), acc1);
        acc2 = fmaf(c3, bflo(r3.y), acc2); acc3 = fmaf(c3, bfhi(r3.y), acc3);
        acc4 = fmaf(c3, bflo(r3.z), acc4); acc5 = fmaf(c3, bfhi(r3.z), acc5);
        acc6 = fmaf(c3, bflo(r3.w), acc6); acc7 = fmaf(c3, bfhi(r3.w), acc7);
    }

    f4v o0 = {acc0, acc1, acc2, acc3};
    f4v o1 = {acc4, acc5, acc6, acc7};
    __builtin_nontemporal_store(o0, (f4v*)orow);
    __builtin_nontemporal_store(o1, (f4v*)(orow + 4));
}

extern "C" void kernel_launch(void* const* d_in, const int* in_sizes, int n_in,
                              void* d_out, int out_size, void* d_ws, size_t ws_size,
                              hipStream_t stream) {
    const float* g = (const float*)d_in[0];   // graph_info [N,N]
    const float* h = (const float*)d_in[1];   // h [N,D]
    const float* P = (const float*)d_in[2];   // P [D,H]
    float* out = (float*)d_out;               // [N,D] fp32

    // ws layout: w fp32 [N,3] at 0 (48 KB); bf16 h copy [N,D] at 64 KB (4 MB)
    float* w = (float*)d_ws;
    unsigned short* hb = (unsigned short*)((char*)d_ws + 65536);

    prep_kernel<<<(NN * 64) / 256, 256, 0, stream>>>(h, P, w, hb);
    att_agg_kernel<<<NN / 4, 256, 0, stream>>>(g, hb, w, out);
}